// Round 1
// baseline (102.380 us; speedup 1.0000x reference)
//
#include <hip/hip_runtime.h>

// Problem constants (match the reference).
constexpr int B = 32, C = 256, H = 56, W = 56, K = 4;
constexpr int HW = H * W;                 // 3136 floats per (b,c) plane
constexpr int BC = B * C;                 // 8192 planes
constexpr long long IMG = (long long)BC * HW;  // 25,690,112 elements

// One block per (b,c) plane. 256 threads stream the plane as float4.
__global__ __launch_bounds__(256) void sk_fuse_kernel(
    const float* __restrict__ x0, const float* __restrict__ x1,
    const float* __restrict__ x2, const float* __restrict__ x3,
    const float* __restrict__ logits,        // [K, B, C] = [K, BC]
    float* __restrict__ out,                 // [B, C, H, W]
    float* __restrict__ s_out,               // [B, C]
    float* __restrict__ usum_out)            // [B, C]
{
    const int bc = blockIdx.x;               // plane id in [0, BC)

    // ---- softmax over K=4 logits for this (b,c) (uniform across block) ----
    const float l0 = logits[0 * BC + bc];
    const float l1 = logits[1 * BC + bc];
    const float l2 = logits[2 * BC + bc];
    const float l3 = logits[3 * BC + bc];
    const float m  = fmaxf(fmaxf(l0, l1), fmaxf(l2, l3));
    const float e0 = expf(l0 - m);
    const float e1 = expf(l1 - m);
    const float e2 = expf(l2 - m);
    const float e3 = expf(l3 - m);
    const float inv = 1.0f / (e0 + e1 + e2 + e3);
    const float w0 = e0 * inv, w1 = e1 * inv, w2 = e2 * inv, w3 = e3 * inv;

    // ---- stream the plane: out = sum_k w_k * x_k ; usum += sum_k x_k ----
    const size_t base = (size_t)bc * HW;
    const float4* __restrict__ p0 = (const float4*)(x0 + base);
    const float4* __restrict__ p1 = (const float4*)(x1 + base);
    const float4* __restrict__ p2 = (const float4*)(x2 + base);
    const float4* __restrict__ p3 = (const float4*)(x3 + base);
    float4* __restrict__ po = (float4*)(out + base);

    constexpr int NV = HW / 4;               // 784 float4 per plane
    float usum = 0.0f;

    for (int i = threadIdx.x; i < NV; i += 256) {
        const float4 a = p0[i];
        const float4 b = p1[i];
        const float4 c = p2[i];
        const float4 d = p3[i];
        float4 o;
        o.x = w0 * a.x + w1 * b.x + w2 * c.x + w3 * d.x;
        o.y = w0 * a.y + w1 * b.y + w2 * c.y + w3 * d.y;
        o.z = w0 * a.z + w1 * b.z + w2 * c.z + w3 * d.z;
        o.w = w0 * a.w + w1 * b.w + w2 * c.w + w3 * d.w;
        po[i] = o;
        usum += (a.x + b.x + c.x + d.x)
              + (a.y + b.y + c.y + d.y)
              + (a.z + b.z + c.z + d.z)
              + (a.w + b.w + c.w + d.w);
    }

    // ---- block reduction of usum: wave shuffle then LDS across 4 waves ----
    #pragma unroll
    for (int off = 32; off > 0; off >>= 1)
        usum += __shfl_down(usum, off, 64);

    __shared__ float wsum[4];
    const int lane = threadIdx.x & 63;
    const int wid  = threadIdx.x >> 6;
    if (lane == 0) wsum[wid] = usum;
    __syncthreads();
    if (threadIdx.x == 0) {
        const float t = wsum[0] + wsum[1] + wsum[2] + wsum[3];
        usum_out[bc] = t;
        s_out[bc]    = t * (1.0f / HW);
    }
}

extern "C" void kernel_launch(void* const* d_in, const int* in_sizes, int n_in,
                              void* d_out, int out_size, void* d_ws, size_t ws_size,
                              hipStream_t stream) {
    const float* x0     = (const float*)d_in[0];
    const float* x1     = (const float*)d_in[1];
    const float* x2     = (const float*)d_in[2];
    const float* x3     = (const float*)d_in[3];
    const float* logits = (const float*)d_in[4];

    float* out      = (float*)d_out;          // [B,C,H,W]
    float* s_out    = out + IMG;              // [B,C]
    float* usum_out = s_out + BC;             // [B,C]

    sk_fuse_kernel<<<BC, 256, 0, stream>>>(x0, x1, x2, x3, logits,
                                           out, s_out, usum_out);
}

// Round 3
// 94.226 us; speedup vs baseline: 1.0865x; 1.0865x over previous
//
#include <hip/hip_runtime.h>

// Problem constants (match the reference).
constexpr int B = 32, C = 256, H = 56, W = 56, K = 4;
constexpr int HW = H * W;                 // 3136 floats per (b,c) plane
constexpr int BC = B * C;                 // 8192 planes
constexpr long long IMG = (long long)BC * HW;  // 25,690,112 elements

// Native clang vector type — accepted by __builtin_nontemporal_store
// (HIP_vector_type float4 is not).
typedef float f4 __attribute__((ext_vector_type(4)));

// One block per (b,c) plane. 256 threads stream the plane as float4.
// NV = 784 float4 per plane = 3 full rounds of 256 + 16-vector tail.
__global__ __launch_bounds__(256) void sk_fuse_kernel(
    const float* __restrict__ x0, const float* __restrict__ x1,
    const float* __restrict__ x2, const float* __restrict__ x3,
    const float* __restrict__ logits,        // [K, B, C] = [K, BC]
    float* __restrict__ out,                 // [B, C, H, W]
    float* __restrict__ s_out,               // [B, C]
    float* __restrict__ usum_out)            // [B, C]
{
    const int bc  = blockIdx.x;              // plane id in [0, BC)
    const int tid = threadIdx.x;

    // ---- softmax over K=4 logits for this (b,c) (uniform across block) ----
    const float l0 = logits[0 * BC + bc];
    const float l1 = logits[1 * BC + bc];
    const float l2 = logits[2 * BC + bc];
    const float l3 = logits[3 * BC + bc];
    const float m  = fmaxf(fmaxf(l0, l1), fmaxf(l2, l3));
    const float e0 = expf(l0 - m);
    const float e1 = expf(l1 - m);
    const float e2 = expf(l2 - m);
    const float e3 = expf(l3 - m);
    const float inv = 1.0f / (e0 + e1 + e2 + e3);
    const float w0 = e0 * inv, w1 = e1 * inv, w2 = e2 * inv, w3 = e3 * inv;

    const size_t base = (size_t)bc * HW;
    const f4* __restrict__ p0 = (const f4*)(x0 + base);
    const f4* __restrict__ p1 = (const f4*)(x1 + base);
    const f4* __restrict__ p2 = (const f4*)(x2 + base);
    const f4* __restrict__ p3 = (const f4*)(x3 + base);
    f4* __restrict__ po = (f4*)(out + base);

    // ---- issue ALL loads up front (12 per thread + predicated tail) ----
    const int i0 = tid, i1 = tid + 256, i2 = tid + 512;
    const f4 a0 = p0[i0], b0 = p1[i0], c0 = p2[i0], d0 = p3[i0];
    const f4 a1 = p0[i1], b1 = p1[i1], c1 = p2[i1], d1 = p3[i1];
    const f4 a2 = p0[i2], b2 = p1[i2], c2 = p2[i2], d2 = p3[i2];

    const bool tail = (tid < 16);
    const int i3 = 768 + (tid & 15);
    f4 a3 = 0.0f, b3 = 0.0f, c3 = 0.0f, d3 = 0.0f;
    if (tail) { a3 = p0[i3]; b3 = p1[i3]; c3 = p2[i3]; d3 = p3[i3]; }

    float usum = 0.0f;

    auto fuse = [&](const f4& a, const f4& b,
                    const f4& c, const f4& d) -> f4 {
        f4 o;
        o.x = w0 * a.x + w1 * b.x + w2 * c.x + w3 * d.x;
        o.y = w0 * a.y + w1 * b.y + w2 * c.y + w3 * d.y;
        o.z = w0 * a.z + w1 * b.z + w2 * c.z + w3 * d.z;
        o.w = w0 * a.w + w1 * b.w + w2 * c.w + w3 * d.w;
        usum += (a.x + b.x + c.x + d.x)
              + (a.y + b.y + c.y + d.y)
              + (a.z + b.z + c.z + d.z)
              + (a.w + b.w + c.w + d.w);
        return o;
    };

    // ---- fuse + non-temporal stores (output is never re-read) ----
    {
        const f4 o = fuse(a0, b0, c0, d0);
        __builtin_nontemporal_store(o, &po[i0]);
    }
    {
        const f4 o = fuse(a1, b1, c1, d1);
        __builtin_nontemporal_store(o, &po[i1]);
    }
    {
        const f4 o = fuse(a2, b2, c2, d2);
        __builtin_nontemporal_store(o, &po[i2]);
    }
    if (tail) {
        const f4 o = fuse(a3, b3, c3, d3);
        __builtin_nontemporal_store(o, &po[i3]);
    }

    // ---- block reduction of usum: wave shuffle then LDS across 4 waves ----
    #pragma unroll
    for (int off = 32; off > 0; off >>= 1)
        usum += __shfl_down(usum, off, 64);

    __shared__ float wsum[4];
    const int lane = tid & 63;
    const int wid  = tid >> 6;
    if (lane == 0) wsum[wid] = usum;
    __syncthreads();
    if (tid == 0) {
        const float t = wsum[0] + wsum[1] + wsum[2] + wsum[3];
        usum_out[bc] = t;
        s_out[bc]    = t * (1.0f / HW);
    }
}

extern "C" void kernel_launch(void* const* d_in, const int* in_sizes, int n_in,
                              void* d_out, int out_size, void* d_ws, size_t ws_size,
                              hipStream_t stream) {
    const float* x0     = (const float*)d_in[0];
    const float* x1     = (const float*)d_in[1];
    const float* x2     = (const float*)d_in[2];
    const float* x3     = (const float*)d_in[3];
    const float* logits = (const float*)d_in[4];

    float* out      = (float*)d_out;          // [B,C,H,W]
    float* s_out    = out + IMG;              // [B,C]
    float* usum_out = s_out + BC;             // [B,C]

    sk_fuse_kernel<<<BC, 256, 0, stream>>>(x0, x1, x2, x3, logits,
                                           out, s_out, usum_out);
}